// Round 12
// baseline (55.223 us; speedup 1.0000x reference)
//
#include <hip/hip_runtime.h>

namespace {
constexpr int   kD      = 95;               // B*5 + C
constexpr int   kCPB    = 64;               // cells per tile
constexpr int   kTPB    = 4;                // tiles per block
constexpr int   kTiles  = 401408 / kCPB;    // 6272
constexpr int   kGrid   = kTiles / kTPB;    // 1568 (exact)
constexpr int   kF4PT   = kCPB * kD / 4;    // 1520 float4s per tile
constexpr float kS      = 28.0f;
}

typedef float vf4 __attribute__((ext_vector_type(4)));

struct TileRegs { vf4 P0,P1,P2,P3,P4,P5, T0,T1,T2,T3,T4,T5; };

__device__ __forceinline__ void load_tile(const float* __restrict__ pred,
                                          const float* __restrict__ targ,
                                          int tile, int tid, TileRegs& R)
{
    const vf4* p4 = reinterpret_cast<const vf4*>(pred) + (size_t)tile * kF4PT;
    const vf4* t4 = reinterpret_cast<const vf4*>(targ) + (size_t)tile * kF4PT;
    R.P0 = __builtin_nontemporal_load(&p4[tid]);         R.T0 = t4[tid];
    R.P1 = __builtin_nontemporal_load(&p4[tid +  256]);  R.T1 = t4[tid +  256];
    R.P2 = __builtin_nontemporal_load(&p4[tid +  512]);  R.T2 = t4[tid +  512];
    R.P3 = __builtin_nontemporal_load(&p4[tid +  768]);  R.T3 = t4[tid +  768];
    R.P4 = __builtin_nontemporal_load(&p4[tid + 1024]);  R.T4 = t4[tid + 1024];
    if (tid < 240) {                                     // 1520 = 5*256 + 240
        R.P5 = __builtin_nontemporal_load(&p4[tid + 1280]);
        R.T5 = t4[tid + 1280];
    }
}

// stage one float4-pair: d = p - t raw into LDS; rare head-staging of t
__device__ __forceinline__ void stage1(const vf4 p, const vf4 t, const int i,
                                       vf4* __restrict__ s_d4,
                                       float* __restrict__ s_t)
{
    s_d4[i] = p - t;                       // aligned ds_write_b128
    const int v   = i * 4;
    const int cl0 = v / kD;                // magic-mul const div
    const int j0  = v - cl0 * kD;
    if (j0 < 7 || j0 >= kD - 3) {          // f4 overlaps a cell head [0,7)
        #pragma unroll
        for (int c = 0; c < 4; ++c) {
            const int  jj   = j0 + c;
            const bool wrap = (jj >= kD);
            const int  j    = wrap ? jj - kD : jj;
            const int  cl   = cl0 + (wrap ? 1 : 0);
            if (j < 7) s_t[cl * 7 + j] = t[c];
        }
    }
}

__device__ __forceinline__ void stage_tile(const TileRegs& R, int tid,
                                           vf4* __restrict__ s_d4,
                                           float* __restrict__ s_t)
{
    stage1(R.P0, R.T0, tid,        s_d4, s_t);
    stage1(R.P1, R.T1, tid +  256, s_d4, s_t);
    stage1(R.P2, R.T2, tid +  512, s_d4, s_t);
    stage1(R.P3, R.T3, tid +  768, s_d4, s_t);
    stage1(R.P4, R.T4, tid + 1024, s_d4, s_t);
    if (tid < 240) stage1(R.P5, R.T5, tid + 1280, s_d4, s_t);
}

__device__ __forceinline__ float compute_iou(
    float bx, float by, float bw, float bh,
    float t1x, float t1y, float t2x, float t2y, float area_t)
{
    const float p1x = bx * (1.0f / kS) - bw * 0.5f;
    const float p1y = by * (1.0f / kS) - bh * 0.5f;
    const float p2x = bx * (1.0f / kS) + bw * 0.5f;
    const float p2y = by * (1.0f / kS) + bh * 0.5f;
    const float ltx = fmaxf(p1x, t1x);
    const float lty = fmaxf(p1y, t1y);
    const float rbx = fminf(p2x, t2x);
    const float rby = fminf(p2y, t2y);
    const float wx  = fmaxf(rbx - ltx, 0.0f);
    const float wy  = fmaxf(rby - lty, 0.0f);
    const float inter  = wx * wy;
    const float area_p = (p2x - p1x) * (p2y - p1y);
    return inter / (area_p + area_t - inter);
}

// per-tile losses from LDS; all 4 waves share cls, wave 0 does head losses
__device__ __forceinline__ float phaseB(const float* __restrict__ s_d,
                                        const float* __restrict__ s_t,
                                        int lane, int wv)
{
    float acc;
    const int  base = lane * kD;
    const bool obj  = (s_t[lane * 7 + 0] > 0.0f);
    {
        float s2a = 0.0f, s2b = 0.0f;
        const int jb = 15 + 20 * wv;
        #pragma unroll
        for (int j = 0; j < 20; j += 2) {
            const float a = s_d[base + jb + j];
            const float b = s_d[base + jb + j + 1];
            s2a = fmaf(a, a, s2a);
            s2b = fmaf(b, b, s2b);
        }
        acc = obj ? (s2a + s2b) : 0.0f;
    }

    if (wv == 0) {
        const float d0 = s_d[base + 0];
        const float d1 = s_d[base + 1];
        const float d2 = s_d[base + 2];

        if (!obj) {
            acc += 0.5f * (d0 * d0 + d1 * d1 + d2 * d2);
        } else {
            const float gx = s_t[lane * 7 + 3], gy = s_t[lane * 7 + 4];
            const float gw = s_t[lane * 7 + 5], gh = s_t[lane * 7 + 6];

            const float cp0 = d0 + 1.0f, cp1 = d1 + 1.0f, cp2 = d2 + 1.0f;
            const float bx0 = s_d[base + 3]  + gx, by0 = s_d[base + 4]  + gy;
            const float bw0 = s_d[base + 5]  + gw, bh0 = s_d[base + 6]  + gh;
            const float bx1 = s_d[base + 7]  + gx, by1 = s_d[base + 8]  + gy;
            const float bw1 = s_d[base + 9]  + gw, bh1 = s_d[base + 10] + gh;
            const float bx2 = s_d[base + 11] + gx, by2 = s_d[base + 12] + gy;
            const float bw2 = s_d[base + 13] + gw, bh2 = s_d[base + 14] + gh;

            const float t1x = gx * (1.0f / kS) - gw * 0.5f;
            const float t1y = gy * (1.0f / kS) - gh * 0.5f;
            const float t2x = gx * (1.0f / kS) + gw * 0.5f;
            const float t2y = gy * (1.0f / kS) + gh * 0.5f;
            const float area_t = (t2x - t1x) * (t2y - t1y);

            const float iou0 = compute_iou(bx0, by0, bw0, bh0, t1x, t1y, t2x, t2y, area_t);
            const float iou1 = compute_iou(bx1, by1, bw1, bh1, t1x, t1y, t2x, t2y, area_t);
            const float iou2 = compute_iou(bx2, by2, bw2, bh2, t1x, t1y, t2x, t2y, area_t);

            // jnp.argmax: first occurrence of max -> strict '>' updates
            int   best = 0;
            float biou = iou0;
            if (iou1 > biou) { best = 1; biou = iou1; }
            if (iou2 > biou) { best = 2; biou = iou2; }

            const float cb  = (best == 0) ? cp0 : ((best == 1) ? cp1 : cp2);
            const float sbx = (best == 0) ? bx0 : ((best == 1) ? bx1 : bx2);
            const float sby = (best == 0) ? by0 : ((best == 1) ? by1 : by2);
            const float sbw = (best == 0) ? bw0 : ((best == 1) ? bw1 : bw2);
            const float sbh = (best == 0) ? bh0 : ((best == 1) ? bh1 : bh2);

            const float dc = cb - biou;                // contain
            acc += dc * dc;

            acc += ((best == 0) ? 0.0f : cp0 * cp0)    // not-contain
                 + ((best == 1) ? 0.0f : cp1 * cp1)
                 + ((best == 2) ? 0.0f : cp2 * cp2);

            const float dx = sbx - gx;                 // location (lambda=5)
            const float dy = sby - gy;
            const float dw = sqrtf(sbw) - sqrtf(gw);
            const float dh = sqrtf(sbh) - sqrtf(gh);
            acc += 5.0f * (dx * dx + dy * dy + dw * dw + dh * dh);
        }
    }
    return acc;
}

__global__ __launch_bounds__(256)
void yolo_loss_kernel(const float* __restrict__ pred,
                      const float* __restrict__ targ,
                      float* __restrict__ partials)
{
    __shared__ vf4   s_d4A[kF4PT], s_d4B[kF4PT];    // 24320 B each
    __shared__ float s_tA[kCPB * 7], s_tB[kCPB * 7]; // 1792 B each
    __shared__ float s_red[4];

    const int tid  = threadIdx.x;
    const int lane = tid & 63;
    const int wv   = tid >> 6;
    const int t0   = blockIdx.x * kTPB;

    float acc = 0.0f;
    TileRegs R;

    // prologue: tile 0 -> buffer A
    load_tile(pred, targ, t0, tid, R);
    stage_tile(R, tid, s_d4A, s_tA);
    __syncthreads();

    // pipelined middle: issue loads(k) early, phaseB(k-1), stage(k) late
    #pragma unroll
    for (int k = 1; k < kTPB; ++k) {
        load_tile(pred, targ, t0 + k, tid, R);          // issue-early
        const bool prevA = ((k - 1) & 1) == 0;
        acc += phaseB(prevA ? (const float*)s_d4A : (const float*)s_d4B,
                      prevA ? s_tA : s_tB, lane, wv);   // compute prev
        if (k & 1) stage_tile(R, tid, s_d4B, s_tB);     // write-late
        else       stage_tile(R, tid, s_d4A, s_tA);
        __syncthreads();
    }

    // epilogue: last tile
    {
        const bool lastA = ((kTPB - 1) & 1) == 0;
        acc += phaseB(lastA ? (const float*)s_d4A : (const float*)s_d4B,
                      lastA ? s_tA : s_tB, lane, wv);
    }

    // ---- reduction: per-block partial --------------------------------------
    #pragma unroll
    for (int off = 32; off > 0; off >>= 1)
        acc += __shfl_down(acc, off, 64);

    if (lane == 0) s_red[wv] = acc;
    __syncthreads();
    if (tid == 0)
        partials[blockIdx.x] = s_red[0] + s_red[1] + s_red[2] + s_red[3];
}

__global__ __launch_bounds__(1024)
void reduce_kernel(const float* __restrict__ partials, float* __restrict__ out)
{
    __shared__ float s_red[16];
    float a = 0.0f;
    for (int i = threadIdx.x; i < kGrid; i += 1024) a += partials[i];
    #pragma unroll
    for (int off = 32; off > 0; off >>= 1)
        a += __shfl_down(a, off, 64);
    const int wave = threadIdx.x >> 6;
    const int lane = threadIdx.x & 63;
    if (lane == 0) s_red[wave] = a;
    __syncthreads();
    if (threadIdx.x == 0) {
        float s = 0.0f;
        #pragma unroll
        for (int w = 0; w < 16; ++w) s += s_red[w];
        out[0] = s * (1.0f / 512.0f);
    }
}

extern "C" void kernel_launch(void* const* d_in, const int* in_sizes, int n_in,
                              void* d_out, int out_size, void* d_ws, size_t ws_size,
                              hipStream_t stream) {
    const float* pred = (const float*)d_in[0];
    const float* targ = (const float*)d_in[1];
    float* out = (float*)d_out;
    float* ws  = (float*)d_ws;

    yolo_loss_kernel<<<kGrid, 256, 0, stream>>>(pred, targ, ws);
    reduce_kernel<<<1, 1024, 0, stream>>>(ws, out);
}

// Round 13
// 52.469 us; speedup vs baseline: 1.0525x; 1.0525x over previous
//
#include <hip/hip_runtime.h>

namespace {
constexpr int   kD      = 95;               // B*5 + C
constexpr int   kCPB    = 64;               // cells per block
constexpr int   kBlocks = 401408 / kCPB;    // 6272 (exact)
constexpr int   kF4PB   = kCPB * kD / 4;    // 1520 (exact)
constexpr float kS      = 28.0f;
}

typedef float vf4 __attribute__((ext_vector_type(4)));

// stage one float4-pair: d = p - t raw into LDS; rare head-staging of t
__device__ __forceinline__ void stage(const vf4 p, const vf4 t, const int i,
                                      vf4* __restrict__ s_d4,
                                      float* __restrict__ s_t)
{
    s_d4[i] = p - t;                       // aligned ds_write_b128
    const int v   = i * 4;
    const int cl0 = v / kD;                // magic-mul const div
    const int j0  = v - cl0 * kD;
    if (j0 < 7 || j0 >= kD - 3) {          // f4 overlaps a cell head [0,7)
        #pragma unroll
        for (int c = 0; c < 4; ++c) {
            const int  jj   = j0 + c;
            const bool wrap = (jj >= kD);
            const int  j    = wrap ? jj - kD : jj;
            const int  cl   = cl0 + (wrap ? 1 : 0);
            if (j < 7) s_t[cl * 7 + j] = t[c];
        }
    }
}

__device__ __forceinline__ float compute_iou(
    float bx, float by, float bw, float bh,
    float t1x, float t1y, float t2x, float t2y, float area_t)
{
    const float p1x = bx * (1.0f / kS) - bw * 0.5f;
    const float p1y = by * (1.0f / kS) - bh * 0.5f;
    const float p2x = bx * (1.0f / kS) + bw * 0.5f;
    const float p2y = by * (1.0f / kS) + bh * 0.5f;
    const float ltx = fmaxf(p1x, t1x);
    const float lty = fmaxf(p1y, t1y);
    const float rbx = fminf(p2x, t2x);
    const float rby = fminf(p2y, t2y);
    const float wx  = fmaxf(rbx - ltx, 0.0f);
    const float wy  = fmaxf(rby - lty, 0.0f);
    const float inter  = wx * wy;
    const float area_p = (p2x - p1x) * (p2y - p1y);
    return inter / (area_p + area_t - inter);
}

__global__ __launch_bounds__(256)
void yolo_loss_kernel(const float* __restrict__ pred,
                      const float* __restrict__ targ,
                      float* __restrict__ partials)
{
    __shared__ vf4   s_d4[kF4PB];          // 24320 B: raw d = p - t
    __shared__ float s_t[kCPB * 7];        //  1792 B: per-cell {t0,_,_,gx,gy,gw,gh}
    __shared__ float s_red[4];
    float* s_d = reinterpret_cast<float*>(s_d4);

    const int tid = threadIdx.x;
    const size_t base4 = (size_t)blockIdx.x * kF4PB;
    const vf4* p4 = reinterpret_cast<const vf4*>(pred) + base4;
    const vf4* t4 = reinterpret_cast<const vf4*>(targ) + base4;

    // ---- phase A: all 12 loads issued up front, then stage ------------------
    // trips: i = tid + 256k, k=0..4 full; k=5 only tid<240 (1520 = 5*256+240)
    const int i0 = tid,        i1 = tid + 256;
    const int i2 = tid + 512,  i3 = tid + 768;
    const int i4 = tid + 1024, i5 = tid + 1280;
    const bool tail = (tid < 240);

    const vf4 P0 = __builtin_nontemporal_load(&p4[i0]);  const vf4 T0 = t4[i0];
    const vf4 P1 = __builtin_nontemporal_load(&p4[i1]);  const vf4 T1 = t4[i1];
    const vf4 P2 = __builtin_nontemporal_load(&p4[i2]);  const vf4 T2 = t4[i2];
    const vf4 P3 = __builtin_nontemporal_load(&p4[i3]);  const vf4 T3 = t4[i3];
    const vf4 P4 = __builtin_nontemporal_load(&p4[i4]);  const vf4 T4 = t4[i4];
    vf4 P5, T5;
    if (tail) {
        P5 = __builtin_nontemporal_load(&p4[i5]);
        T5 = t4[i5];
    }

    stage(P0, T0, i0, s_d4, s_t);
    stage(P1, T1, i1, s_d4, s_t);
    stage(P2, T2, i2, s_d4, s_t);
    stage(P3, T3, i3, s_d4, s_t);
    stage(P4, T4, i4, s_d4, s_t);
    if (tail) stage(P5, T5, i5, s_d4, s_t);

    __syncthreads();

    // ---- phase B: all 4 waves share the work --------------------------------
    // cls: wave w sums fields j in [15+20w, 35+20w) for cell = lane.
    // s_d reads stride 95 across lanes (coprime with 32 -> 2 lanes/bank).
    const int lane = tid & 63;
    const int wv   = tid >> 6;
    float acc = 0.0f;
    {
        const int  base = lane * kD;
        const bool obj  = (s_t[lane * 7 + 0] > 0.0f);
        float s2a = 0.0f, s2b = 0.0f;
        const int jb = 15 + 20 * wv;
        #pragma unroll
        for (int j = 0; j < 20; j += 2) {
            const float a = s_d[base + jb + j];
            const float b = s_d[base + jb + j + 1];
            s2a = fmaf(a, a, s2a);
            s2b = fmaf(b, b, s2b);
        }
        acc = obj ? (s2a + s2b) : 0.0f;
    }

    if (wv == 0) {
        const int base = lane * kD;
        const float tc0 = s_t[lane * 7 + 0];
        const bool  obj = (tc0 > 0.0f);

        const float d0 = s_d[base + 0];
        const float d1 = s_d[base + 1];
        const float d2 = s_d[base + 2];

        if (!obj) {
            // noobj conf: 0.5 * sum d^2  (conf_t == 0 -> d == conf_p)
            acc += 0.5f * (d0 * d0 + d1 * d1 + d2 * d2);
        } else {
            const float gx = s_t[lane * 7 + 3], gy = s_t[lane * 7 + 4];
            const float gw = s_t[lane * 7 + 5], gh = s_t[lane * 7 + 6];

            // reconstruct pred: p = d + t; conf_t = 1, box_t = gt tiled
            const float cp0 = d0 + 1.0f, cp1 = d1 + 1.0f, cp2 = d2 + 1.0f;
            const float bx0 = s_d[base + 3]  + gx, by0 = s_d[base + 4]  + gy;
            const float bw0 = s_d[base + 5]  + gw, bh0 = s_d[base + 6]  + gh;
            const float bx1 = s_d[base + 7]  + gx, by1 = s_d[base + 8]  + gy;
            const float bw1 = s_d[base + 9]  + gw, bh1 = s_d[base + 10] + gh;
            const float bx2 = s_d[base + 11] + gx, by2 = s_d[base + 12] + gy;
            const float bw2 = s_d[base + 13] + gw, bh2 = s_d[base + 14] + gh;

            const float t1x = gx * (1.0f / kS) - gw * 0.5f;
            const float t1y = gy * (1.0f / kS) - gh * 0.5f;
            const float t2x = gx * (1.0f / kS) + gw * 0.5f;
            const float t2y = gy * (1.0f / kS) + gh * 0.5f;
            const float area_t = (t2x - t1x) * (t2y - t1y);

            const float iou0 = compute_iou(bx0, by0, bw0, bh0, t1x, t1y, t2x, t2y, area_t);
            const float iou1 = compute_iou(bx1, by1, bw1, bh1, t1x, t1y, t2x, t2y, area_t);
            const float iou2 = compute_iou(bx2, by2, bw2, bh2, t1x, t1y, t2x, t2y, area_t);

            // jnp.argmax: first occurrence of max -> strict '>' updates
            int   best = 0;
            float biou = iou0;
            if (iou1 > biou) { best = 1; biou = iou1; }
            if (iou2 > biou) { best = 2; biou = iou2; }

            const float cb  = (best == 0) ? cp0 : ((best == 1) ? cp1 : cp2);
            const float sbx = (best == 0) ? bx0 : ((best == 1) ? bx1 : bx2);
            const float sby = (best == 0) ? by0 : ((best == 1) ? by1 : by2);
            const float sbw = (best == 0) ? bw0 : ((best == 1) ? bw1 : bw2);
            const float sbh = (best == 0) ? bh0 : ((best == 1) ? bh1 : bh2);

            const float dc = cb - biou;                // contain
            acc += dc * dc;

            acc += ((best == 0) ? 0.0f : cp0 * cp0)    // not-contain
                 + ((best == 1) ? 0.0f : cp1 * cp1)
                 + ((best == 2) ? 0.0f : cp2 * cp2);

            const float dx = sbx - gx;                 // location (lambda=5)
            const float dy = sby - gy;
            const float dw = sqrtf(sbw) - sqrtf(gw);
            const float dh = sqrtf(sbh) - sqrtf(gh);
            acc += 5.0f * (dx * dx + dy * dy + dw * dw + dh * dh);
        }
    }

    // ---- reduction: per-block partial ---------------------------------------
    #pragma unroll
    for (int off = 32; off > 0; off >>= 1)
        acc += __shfl_down(acc, off, 64);

    if (lane == 0) s_red[wv] = acc;
    __syncthreads();
    if (tid == 0)
        partials[blockIdx.x] = s_red[0] + s_red[1] + s_red[2] + s_red[3];
}

__global__ __launch_bounds__(1024)
void reduce_kernel(const float* __restrict__ partials, float* __restrict__ out)
{
    __shared__ float s_red[16];
    float a = 0.0f;
    for (int i = threadIdx.x; i < kBlocks; i += 1024) a += partials[i];
    #pragma unroll
    for (int off = 32; off > 0; off >>= 1)
        a += __shfl_down(a, off, 64);
    const int wave = threadIdx.x >> 6;
    const int lane = threadIdx.x & 63;
    if (lane == 0) s_red[wave] = a;
    __syncthreads();
    if (threadIdx.x == 0) {
        float s = 0.0f;
        #pragma unroll
        for (int w = 0; w < 16; ++w) s += s_red[w];
        out[0] = s * (1.0f / 512.0f);
    }
}

extern "C" void kernel_launch(void* const* d_in, const int* in_sizes, int n_in,
                              void* d_out, int out_size, void* d_ws, size_t ws_size,
                              hipStream_t stream) {
    const float* pred = (const float*)d_in[0];
    const float* targ = (const float*)d_in[1];
    float* out = (float*)d_out;
    float* ws  = (float*)d_ws;

    yolo_loss_kernel<<<kBlocks, 256, 0, stream>>>(pred, targ, ws);
    reduce_kernel<<<1, 1024, 0, stream>>>(ws, out);
}